// Round 1
// baseline (401.949 us; speedup 1.0000x reference)
//
#include <hip/hip_runtime.h>
#include <math.h>

#define T_LEN 128
#define BSZ 8
#define DMODEL 512
#define NHEADS 8
#define HDIM 64
#define SCALING 0.125f

// ---------------------------------------------------------------------------
// Kernel A: packed in-projection GEMM -> per-head layouts.
// C[r,j] = sum_m Xsel(j)[r,m] * W[j,m] + bias[j], r in [0,1024), j in [0,1536)
//   j <  512 : q -> qh[i][t][hd]   (scaled by 0.125)
//   j < 1024 : k -> kht[i][hd][t]  (transposed for the score kernel)
//   j < 1536 : v -> vht[i][hd][t]
// i = batch*8 + head, t = r/8, batch = r%8, head = (j%512)/64, hd = j%64
// ---------------------------------------------------------------------------
__global__ __launch_bounds__(256)
void proj_kernel(const float* __restrict__ query,
                 const float* __restrict__ key,
                 const float* __restrict__ value,
                 const float* __restrict__ W,
                 const float* __restrict__ bias,
                 float* __restrict__ qh,
                 float* __restrict__ kht,
                 float* __restrict__ vht) {
  __shared__ float Xs[16][68];   // [k][row], pad 68 keeps float4 alignment
  __shared__ float Ws[16][68];
  const int r0 = blockIdx.y * 64;
  const int c0 = blockIdx.x * 64;
  const int g = c0 >> 9;  // 0=q,1=k,2=v (uniform per block)
  const float* __restrict__ X = (g == 0) ? query : (g == 1) ? key : value;
  const int tid = threadIdx.x;
  const int lrow = tid >> 2;        // 0..63
  const int lk4 = (tid & 3) * 4;    // 0,4,8,12
  const int tr = tid >> 4;          // 0..15
  const int tc = tid & 15;          // 0..15

  float acc[4][4] = {};
  for (int kt = 0; kt < 512; kt += 16) {
    float4 xv = *(const float4*)&X[(r0 + lrow) * 512 + kt + lk4];
    float4 wv = *(const float4*)&W[(c0 + lrow) * 512 + kt + lk4];
    __syncthreads();
    Xs[lk4 + 0][lrow] = xv.x; Xs[lk4 + 1][lrow] = xv.y;
    Xs[lk4 + 2][lrow] = xv.z; Xs[lk4 + 3][lrow] = xv.w;
    Ws[lk4 + 0][lrow] = wv.x; Ws[lk4 + 1][lrow] = wv.y;
    Ws[lk4 + 2][lrow] = wv.z; Ws[lk4 + 3][lrow] = wv.w;
    __syncthreads();
#pragma unroll
    for (int kk = 0; kk < 16; kk++) {
      float a[4], b[4];
      *(float4*)a = *(const float4*)&Xs[kk][tr * 4];
      *(float4*)b = *(const float4*)&Ws[kk][tc * 4];
#pragma unroll
      for (int ri = 0; ri < 4; ri++)
#pragma unroll
        for (int cj = 0; cj < 4; cj++)
          acc[ri][cj] = fmaf(a[ri], b[cj], acc[ri][cj]);
    }
  }

#pragma unroll
  for (int ri = 0; ri < 4; ri++) {
    const int r = r0 + tr * 4 + ri;
    const int t = r >> 3;
    const int batch = r & 7;
#pragma unroll
    for (int cj = 0; cj < 4; cj++) {
      const int j = c0 + tc * 4 + cj;
      float val = acc[ri][cj] + bias[j];
      const int jj = j & 511;
      const int head = jj >> 6;
      const int hd = jj & 63;
      const int i = batch * 8 + head;
      if (g == 0)      qh[((i << 7) + t) * 64 + hd] = val * SCALING;
      else if (g == 1) kht[((i << 6) + hd) * 128 + t] = val;
      else             vht[((i << 6) + hd) * 128 + t] = val;
    }
  }
}

// ---------------------------------------------------------------------------
// Kernel B: the trilinear cube, fused with bias add and mean/max over c.
// One block per (batch, a); loops 8 heads. Per head:
//   S[b,c] = sum_t (k[b,t]*qa[t]) * v[c,t] + bias[batch,a,b,c]
//   fused[i,a,b] = mean_c S + max_c S
// Kt/Vt staged in LDS as [t][b] (64x128 each, 64 KB total).
// Thread (tr,tc) owns an 8x8 (b,c) tile; 64 FMA per t-step -> VALU-bound.
// ---------------------------------------------------------------------------
__global__ __launch_bounds__(256)
void score_kernel(const float* __restrict__ qh,
                  const float* __restrict__ kht,
                  const float* __restrict__ vht,
                  const float* __restrict__ cbias,
                  float* __restrict__ fused) {
  __shared__ float Kt[64][128];
  __shared__ float Vt[64][128];
  const int bid = blockIdx.x;
  const int batch = bid >> 7;
  const int a = bid & 127;
  const int tid = threadIdx.x;
  const int tr = tid >> 4, tc = tid & 15;
  const int b0 = tr * 8, c0 = tc * 8;
  const float* __restrict__ bp =
      cbias + ((size_t)(batch * 128 + a)) * 128 * 128;

  for (int h = 0; h < 8; h++) {
    const int i = batch * 8 + h;
    const float* __restrict__ kbase = kht + (size_t)i * 64 * 128;
    const float* __restrict__ vbase = vht + (size_t)i * 64 * 128;
    const float* __restrict__ qa = qh + ((size_t)i * 128 + a) * 64;
    __syncthreads();  // protect previous iteration's reads
#pragma unroll
    for (int k = 0; k < 8; k++) {
      const int f4 = k * 256 + tid;      // 0..2047 float4 slots
      const int hd = f4 >> 5;            // row (t index in LDS)
      const int b = (f4 & 31) * 4;
      const float qv = qa[hd];
      float4 kv = *(const float4*)&kbase[hd * 128 + b];
      float4 vv = *(const float4*)&vbase[hd * 128 + b];
      kv.x *= qv; kv.y *= qv; kv.z *= qv; kv.w *= qv;
      *(float4*)&Kt[hd][b] = kv;
      *(float4*)&Vt[hd][b] = vv;
    }
    __syncthreads();

    float acc[8][8] = {};
    for (int t = 0; t < 64; t++) {
      float ka[8], vb[8];
      *(float4*)&ka[0] = *(const float4*)&Kt[t][b0];
      *(float4*)&ka[4] = *(const float4*)&Kt[t][b0 + 4];
      *(float4*)&vb[0] = *(const float4*)&Vt[t][c0];
      *(float4*)&vb[4] = *(const float4*)&Vt[t][c0 + 4];
#pragma unroll
      for (int ib = 0; ib < 8; ib++)
#pragma unroll
        for (int ic = 0; ic < 8; ic++)
          acc[ib][ic] = fmaf(ka[ib], vb[ic], acc[ib][ic]);
    }

    float fsum[8], fmax[8];
#pragma unroll
    for (int ib = 0; ib < 8; ib++) {
      const int b = b0 + ib;
      float bb[8];
      *(float4*)&bb[0] = *(const float4*)&bp[b * 128 + c0];
      *(float4*)&bb[4] = *(const float4*)&bp[b * 128 + c0 + 4];
      float s = 0.0f, mx = -INFINITY;
#pragma unroll
      for (int ic = 0; ic < 8; ic++) {
        const float v = acc[ib][ic] + bb[ic];
        s += v;
        mx = fmaxf(mx, v);
      }
      fsum[ib] = s;
      fmax[ib] = mx;
    }
    // reduce across the 16 threads (lanes tc=0..15 within each wave group)
#pragma unroll
    for (int off = 8; off >= 1; off >>= 1) {
#pragma unroll
      for (int ib = 0; ib < 8; ib++) {
        fsum[ib] += __shfl_xor(fsum[ib], off, 64);
        fmax[ib] = fmaxf(fmax[ib], __shfl_xor(fmax[ib], off, 64));
      }
    }
    if (tc == 0) {
#pragma unroll
      for (int ib = 0; ib < 8; ib++)
        fused[((size_t)i * 128 + a) * 128 + b0 + ib] =
            fsum[ib] * (1.0f / 128.0f) + fmax[ib];
    }
  }
}

// ---------------------------------------------------------------------------
// Kernel C: softmax over b + attn[i,a,:] = sum_b w[b] * q[i,b,:]
// One wave per (i, a). Writes attn in (T, B, 512) layout for the out-proj.
// ---------------------------------------------------------------------------
__global__ __launch_bounds__(64)
void softmax_attn_kernel(const float* __restrict__ fused,
                         const float* __restrict__ qh,
                         float* __restrict__ attn) {
  const int bid = blockIdx.x;  // i*128 + a
  const int i = bid >> 7;
  const int a = bid & 127;
  const int lane = threadIdx.x;
  const float* __restrict__ fr = fused + (size_t)bid * 128;
  float f0 = fr[lane], f1 = fr[lane + 64];
  float m = fmaxf(f0, f1);
#pragma unroll
  for (int off = 32; off >= 1; off >>= 1) m = fmaxf(m, __shfl_xor(m, off, 64));
  const float e0 = expf(f0 - m), e1 = expf(f1 - m);
  float s = e0 + e1;
#pragma unroll
  for (int off = 32; off >= 1; off >>= 1) s += __shfl_xor(s, off, 64);
  const float inv = 1.0f / s;
  __shared__ float w[128];
  w[lane] = e0 * inv;
  w[lane + 64] = e1 * inv;
  __syncthreads();
  const float* __restrict__ qp = qh + (size_t)i * 128 * 64 + lane;
  float acc = 0.0f;
#pragma unroll 4
  for (int b = 0; b < 128; b++) acc = fmaf(w[b], qp[b * 64], acc);
  const int batch = i >> 3, head = i & 7;
  attn[((size_t)a * 8 + batch) * 512 + head * 64 + lane] = acc;
}

// ---------------------------------------------------------------------------
// Kernel D: output projection. out[r,j] = sum_m attn[r,m]*out_w[j,m] + out_b[j]
// ---------------------------------------------------------------------------
__global__ __launch_bounds__(256)
void outproj_kernel(const float* __restrict__ Xa,
                    const float* __restrict__ W,
                    const float* __restrict__ bias,
                    float* __restrict__ out) {
  __shared__ float Xs[16][68];
  __shared__ float Ws[16][68];
  const int r0 = blockIdx.y * 64;
  const int c0 = blockIdx.x * 64;
  const int tid = threadIdx.x;
  const int lrow = tid >> 2;
  const int lk4 = (tid & 3) * 4;
  const int tr = tid >> 4;
  const int tc = tid & 15;

  float acc[4][4] = {};
  for (int kt = 0; kt < 512; kt += 16) {
    float4 xv = *(const float4*)&Xa[(r0 + lrow) * 512 + kt + lk4];
    float4 wv = *(const float4*)&W[(c0 + lrow) * 512 + kt + lk4];
    __syncthreads();
    Xs[lk4 + 0][lrow] = xv.x; Xs[lk4 + 1][lrow] = xv.y;
    Xs[lk4 + 2][lrow] = xv.z; Xs[lk4 + 3][lrow] = xv.w;
    Ws[lk4 + 0][lrow] = wv.x; Ws[lk4 + 1][lrow] = wv.y;
    Ws[lk4 + 2][lrow] = wv.z; Ws[lk4 + 3][lrow] = wv.w;
    __syncthreads();
#pragma unroll
    for (int kk = 0; kk < 16; kk++) {
      float a[4], b[4];
      *(float4*)a = *(const float4*)&Xs[kk][tr * 4];
      *(float4*)b = *(const float4*)&Ws[kk][tc * 4];
#pragma unroll
      for (int ri = 0; ri < 4; ri++)
#pragma unroll
        for (int cj = 0; cj < 4; cj++)
          acc[ri][cj] = fmaf(a[ri], b[cj], acc[ri][cj]);
    }
  }
#pragma unroll
  for (int ri = 0; ri < 4; ri++) {
    const int r = r0 + tr * 4 + ri;
#pragma unroll
    for (int cj = 0; cj < 4; cj++) {
      const int j = c0 + tc * 4 + cj;
      out[(size_t)r * 512 + j] = acc[ri][cj] + bias[j];
    }
  }
}

extern "C" void kernel_launch(void* const* d_in, const int* in_sizes, int n_in,
                              void* d_out, int out_size, void* d_ws,
                              size_t ws_size, hipStream_t stream) {
  const float* query = (const float*)d_in[0];
  const float* key   = (const float*)d_in[1];
  const float* value = (const float*)d_in[2];
  const float* cbias = (const float*)d_in[3];
  const float* W     = (const float*)d_in[4];
  const float* pb    = (const float*)d_in[5];
  const float* out_w = (const float*)d_in[6];
  const float* out_b = (const float*)d_in[7];
  float* out = (float*)d_out;

  float* ws = (float*)d_ws;
  float* qh     = ws;                           // 64*128*64  = 524288 f
  float* kht    = ws + 524288;                  // 64*64*128  = 524288 f
  float* vht    = ws + 2 * 524288;              // 524288 f
  float* fusedb = ws + 3 * 524288;              // 64*128*128 = 1048576 f
  float* attn   = ws + 3 * 524288 + 1048576;    // 1024*512   = 524288 f

  proj_kernel<<<dim3(24, 16), 256, 0, stream>>>(query, key, value, W, pb, qh,
                                                kht, vht);
  score_kernel<<<1024, 256, 0, stream>>>(qh, kht, vht, cbias, fusedb);
  softmax_attn_kernel<<<8192, 64, 0, stream>>>(fusedb, qh, attn);
  outproj_kernel<<<dim3(8, 16), 256, 0, stream>>>(attn, out_w, out_b, out);
}

// Round 2
// 221.465 us; speedup vs baseline: 1.8150x; 1.8150x over previous
//
#include <hip/hip_runtime.h>
#include <math.h>

#define SCALING 0.125f

typedef __attribute__((ext_vector_type(8))) short short8;
typedef __attribute__((ext_vector_type(4))) float f32x4;

// round-to-nearest-even fp32 -> bf16 (single value)
static __device__ __forceinline__ unsigned short bf16r(float x) {
  unsigned int u = __float_as_uint(x);
  u += 0x7fffu + ((u >> 16) & 1u);
  return (unsigned short)(u >> 16);
}
// pack two fp32 -> bf16x2 (lo in low 16 bits)
static __device__ __forceinline__ unsigned int pk_bf16(float lo, float hi) {
  unsigned int ua = __float_as_uint(lo);
  unsigned int ub = __float_as_uint(hi);
  ua += 0x7fffu + ((ua >> 16) & 1u);
  ub += 0x7fffu + ((ub >> 16) & 1u);
  return (ua >> 16) | (ub & 0xffff0000u);
}

// ---------------------------------------------------------------------------
// Kernel A: packed in-projection GEMM -> per-head layouts.
//   j <  512 : q -> qh[i][t][hd] fp32  (scaled by 0.125)
//   j < 1024 : k -> kh[i][t][hd] fp32
//   j < 1536 : v -> vh[i][t][hd] bf16  (rounded once here)
// i = batch*8 + head, t = r/8, batch = r%8, head = (j%512)/64, hd = j%64
// ---------------------------------------------------------------------------
__global__ __launch_bounds__(256)
void proj_kernel(const float* __restrict__ query,
                 const float* __restrict__ key,
                 const float* __restrict__ value,
                 const float* __restrict__ W,
                 const float* __restrict__ bias,
                 float* __restrict__ qh,
                 float* __restrict__ kh,
                 unsigned short* __restrict__ vh) {
  __shared__ float Xs[16][68];
  __shared__ float Ws[16][68];
  const int r0 = blockIdx.y * 64;
  const int c0 = blockIdx.x * 64;
  const int g = c0 >> 9;  // 0=q,1=k,2=v (uniform per block)
  const float* __restrict__ X = (g == 0) ? query : (g == 1) ? key : value;
  const int tid = threadIdx.x;
  const int lrow = tid >> 2;
  const int lk4 = (tid & 3) * 4;
  const int tr = tid >> 4;
  const int tc = tid & 15;

  float acc[4][4] = {};
  for (int kt = 0; kt < 512; kt += 16) {
    float4 xv = *(const float4*)&X[(r0 + lrow) * 512 + kt + lk4];
    float4 wv = *(const float4*)&W[(c0 + lrow) * 512 + kt + lk4];
    __syncthreads();
    Xs[lk4 + 0][lrow] = xv.x; Xs[lk4 + 1][lrow] = xv.y;
    Xs[lk4 + 2][lrow] = xv.z; Xs[lk4 + 3][lrow] = xv.w;
    Ws[lk4 + 0][lrow] = wv.x; Ws[lk4 + 1][lrow] = wv.y;
    Ws[lk4 + 2][lrow] = wv.z; Ws[lk4 + 3][lrow] = wv.w;
    __syncthreads();
#pragma unroll
    for (int kk = 0; kk < 16; kk++) {
      float a[4], b[4];
      *(float4*)a = *(const float4*)&Xs[kk][tr * 4];
      *(float4*)b = *(const float4*)&Ws[kk][tc * 4];
#pragma unroll
      for (int ri = 0; ri < 4; ri++)
#pragma unroll
        for (int cj = 0; cj < 4; cj++)
          acc[ri][cj] = fmaf(a[ri], b[cj], acc[ri][cj]);
    }
  }

#pragma unroll
  for (int ri = 0; ri < 4; ri++) {
    const int r = r0 + tr * 4 + ri;
    const int t = r >> 3;
    const int batch = r & 7;
#pragma unroll
    for (int cj = 0; cj < 4; cj++) {
      const int j = c0 + tc * 4 + cj;
      float val = acc[ri][cj] + bias[j];
      const int jj = j & 511;
      const int head = jj >> 6;
      const int hd = jj & 63;
      const int i = batch * 8 + head;
      const int idx = ((i << 7) + t) * 64 + hd;
      if (g == 0)      qh[idx] = val * SCALING;
      else if (g == 1) kh[idx] = val;
      else             vh[idx] = bf16r(val);
    }
  }
}

// ---------------------------------------------------------------------------
// Kernel B: trilinear cube via bf16 MFMA, fused bias add + mean/max over c.
// One block per (batch, a); 4 waves; loops 8 heads.
// Per head: S^T[c,b] = sum_hd v[c,hd] * (k[b,hd]*q_a[hd]) ; D rows = c.
// LDS: Vs (A-operand, [c][hd]) and Ks (B-operand, [b][hd]), rows padded to
// 72 bf16 (144 B) -> 2-way bank aliasing only (free).
// Epilogue: bias float4 per fragment (4 consecutive c, fixed b), in-register
// sum/max over c, cross-quad shfl reduce, quad 0 writes fused[i][a][b].
// ---------------------------------------------------------------------------
__global__ __launch_bounds__(256)
void score_kernel(const float* __restrict__ qh,
                  const float* __restrict__ kh,
                  const unsigned short* __restrict__ vh,
                  const float* __restrict__ cbias,
                  float* __restrict__ fused) {
  __shared__ __align__(16) unsigned short Ks[128 * 72];
  __shared__ __align__(16) unsigned short Vs[128 * 72];
  const int bid = blockIdx.x;
  const int batch = bid >> 7;
  const int a = bid & 127;
  const int tid = threadIdx.x;
  const int w = tid >> 6;
  const int lane = tid & 63;
  const int quad = lane >> 4;
  const int n15 = lane & 15;
  const float* __restrict__ bp = cbias + (size_t)(batch * 128 + a) * 16384;

  for (int h = 0; h < 8; ++h) {
    const int i = batch * 8 + h;
    const float* __restrict__ kb = kh + (size_t)i * 8192;
    const uint4* __restrict__ vb4 = (const uint4*)(vh + (size_t)i * 8192);
    const float* __restrict__ qa = qh + ((size_t)i * 128 + a) * 64;

    __syncthreads();  // previous head's fragment reads complete
#pragma unroll
    for (int j = 0; j < 4; ++j) {
      const int gg = j * 256 + tid;       // 0..1023 groups of 8 elements
      const int row = gg >> 3;            // 0..127
      const int col8 = (gg & 7) * 8;      // 0..56
      // V: straight bf16 copy global -> LDS
      *(uint4*)&Vs[row * 72 + col8] = vb4[gg];
      // K*q_a: fp32 mul, round once to bf16
      f32x4 k0 = *(const f32x4*)&kb[8 * gg];
      f32x4 k1 = *(const f32x4*)&kb[8 * gg + 4];
      f32x4 q0 = *(const f32x4*)&qa[col8];
      f32x4 q1 = *(const f32x4*)&qa[col8 + 4];
      k0 *= q0;
      k1 *= q1;
      uint4 pk;
      pk.x = pk_bf16(k0[0], k0[1]);
      pk.y = pk_bf16(k0[2], k0[3]);
      pk.z = pk_bf16(k1[0], k1[1]);
      pk.w = pk_bf16(k1[2], k1[3]);
      *(uint4*)&Ks[row * 72 + col8] = pk;
    }
    __syncthreads();

    // B-operand fragments: b-strip of 32 per wave
    short8 bf[2][2];
#pragma unroll
    for (int jb = 0; jb < 2; ++jb)
#pragma unroll
      for (int kk = 0; kk < 2; ++kk)
        bf[jb][kk] = *(const short8*)&Ks[(w * 32 + jb * 16 + n15) * 72 +
                                         kk * 32 + quad * 8];

    f32x4 acc[8][2];
#pragma unroll
    for (int ic = 0; ic < 8; ++ic)
#pragma unroll
      for (int jb = 0; jb < 2; ++jb)
        acc[ic][jb] = (f32x4){0.f, 0.f, 0.f, 0.f};

#pragma unroll
    for (int ic = 0; ic < 8; ++ic) {
      short8 a0 = *(const short8*)&Vs[(ic * 16 + n15) * 72 + quad * 8];
      short8 a1 = *(const short8*)&Vs[(ic * 16 + n15) * 72 + 32 + quad * 8];
      acc[ic][0] =
          __builtin_amdgcn_mfma_f32_16x16x32_bf16(a0, bf[0][0], acc[ic][0], 0, 0, 0);
      acc[ic][0] =
          __builtin_amdgcn_mfma_f32_16x16x32_bf16(a1, bf[0][1], acc[ic][0], 0, 0, 0);
      acc[ic][1] =
          __builtin_amdgcn_mfma_f32_16x16x32_bf16(a0, bf[1][0], acc[ic][1], 0, 0, 0);
      acc[ic][1] =
          __builtin_amdgcn_mfma_f32_16x16x32_bf16(a1, bf[1][1], acc[ic][1], 0, 0, 0);
    }

    float fsum[2] = {0.f, 0.f};
    float fmx[2] = {-INFINITY, -INFINITY};
#pragma unroll
    for (int ic = 0; ic < 8; ++ic)
#pragma unroll
      for (int jb = 0; jb < 2; ++jb) {
        const int b = w * 32 + jb * 16 + n15;
        f32x4 bb = *(const f32x4*)&bp[b * 128 + ic * 16 + quad * 4];
#pragma unroll
        for (int r = 0; r < 4; ++r) {
          const float v = acc[ic][jb][r] + bb[r];
          fsum[jb] += v;
          fmx[jb] = fmaxf(fmx[jb], v);
        }
      }
#pragma unroll
    for (int off = 16; off <= 32; off <<= 1) {
#pragma unroll
      for (int jb = 0; jb < 2; ++jb) {
        fsum[jb] += __shfl_xor(fsum[jb], off, 64);
        fmx[jb] = fmaxf(fmx[jb], __shfl_xor(fmx[jb], off, 64));
      }
    }
    if (quad == 0) {
      float* fo = fused + ((size_t)i * 128 + a) * 128 + w * 32;
      fo[n15] = fsum[0] * (1.0f / 128.0f) + fmx[0];
      fo[16 + n15] = fsum[1] * (1.0f / 128.0f) + fmx[1];
    }
  }
}

// ---------------------------------------------------------------------------
// Kernel C: softmax over b + attn[i,a,:] = sum_b w[b] * q[i,b,:]
// ---------------------------------------------------------------------------
__global__ __launch_bounds__(64)
void softmax_attn_kernel(const float* __restrict__ fused,
                         const float* __restrict__ qh,
                         float* __restrict__ attn) {
  const int bid = blockIdx.x;  // i*128 + a
  const int i = bid >> 7;
  const int a = bid & 127;
  const int lane = threadIdx.x;
  const float* __restrict__ fr = fused + (size_t)bid * 128;
  float f0 = fr[lane], f1 = fr[lane + 64];
  float m = fmaxf(f0, f1);
#pragma unroll
  for (int off = 32; off >= 1; off >>= 1) m = fmaxf(m, __shfl_xor(m, off, 64));
  const float e0 = expf(f0 - m), e1 = expf(f1 - m);
  float s = e0 + e1;
#pragma unroll
  for (int off = 32; off >= 1; off >>= 1) s += __shfl_xor(s, off, 64);
  const float inv = 1.0f / s;
  __shared__ float w[128];
  w[lane] = e0 * inv;
  w[lane + 64] = e1 * inv;
  __syncthreads();
  const float* __restrict__ qp = qh + (size_t)i * 128 * 64 + lane;
  float acc = 0.0f;
#pragma unroll 4
  for (int b = 0; b < 128; b++) acc = fmaf(w[b], qp[b * 64], acc);
  const int batch = i >> 3, head = i & 7;
  attn[((size_t)a * 8 + batch) * 512 + head * 64 + lane] = acc;
}

// ---------------------------------------------------------------------------
// Kernel D: output projection. out[r,j] = sum_m attn[r,m]*out_w[j,m] + out_b[j]
// ---------------------------------------------------------------------------
__global__ __launch_bounds__(256)
void outproj_kernel(const float* __restrict__ Xa,
                    const float* __restrict__ W,
                    const float* __restrict__ bias,
                    float* __restrict__ out) {
  __shared__ float Xs[16][68];
  __shared__ float Ws[16][68];
  const int r0 = blockIdx.y * 64;
  const int c0 = blockIdx.x * 64;
  const int tid = threadIdx.x;
  const int lrow = tid >> 2;
  const int lk4 = (tid & 3) * 4;
  const int tr = tid >> 4;
  const int tc = tid & 15;

  float acc[4][4] = {};
  for (int kt = 0; kt < 512; kt += 16) {
    float4 xv = *(const float4*)&Xa[(r0 + lrow) * 512 + kt + lk4];
    float4 wv = *(const float4*)&W[(c0 + lrow) * 512 + kt + lk4];
    __syncthreads();
    Xs[lk4 + 0][lrow] = xv.x; Xs[lk4 + 1][lrow] = xv.y;
    Xs[lk4 + 2][lrow] = xv.z; Xs[lk4 + 3][lrow] = xv.w;
    Ws[lk4 + 0][lrow] = wv.x; Ws[lk4 + 1][lrow] = wv.y;
    Ws[lk4 + 2][lrow] = wv.z; Ws[lk4 + 3][lrow] = wv.w;
    __syncthreads();
#pragma unroll
    for (int kk = 0; kk < 16; kk++) {
      float a[4], b[4];
      *(float4*)a = *(const float4*)&Xs[kk][tr * 4];
      *(float4*)b = *(const float4*)&Ws[kk][tc * 4];
#pragma unroll
      for (int ri = 0; ri < 4; ri++)
#pragma unroll
        for (int cj = 0; cj < 4; cj++)
          acc[ri][cj] = fmaf(a[ri], b[cj], acc[ri][cj]);
    }
  }
#pragma unroll
  for (int ri = 0; ri < 4; ri++) {
    const int r = r0 + tr * 4 + ri;
#pragma unroll
    for (int cj = 0; cj < 4; cj++) {
      const int j = c0 + tc * 4 + cj;
      out[(size_t)r * 512 + j] = acc[ri][cj] + bias[j];
    }
  }
}

extern "C" void kernel_launch(void* const* d_in, const int* in_sizes, int n_in,
                              void* d_out, int out_size, void* d_ws,
                              size_t ws_size, hipStream_t stream) {
  const float* query = (const float*)d_in[0];
  const float* key   = (const float*)d_in[1];
  const float* value = (const float*)d_in[2];
  const float* cbias = (const float*)d_in[3];
  const float* W     = (const float*)d_in[4];
  const float* pb    = (const float*)d_in[5];
  const float* out_w = (const float*)d_in[6];
  const float* out_b = (const float*)d_in[7];
  float* out = (float*)d_out;

  float* ws = (float*)d_ws;
  float* qh = ws;                                  // 524288 f
  float* kh = ws + 524288;                         // 524288 f
  unsigned short* vh = (unsigned short*)(ws + 1048576);  // 524288 bf16 = 262144 f
  float* fusedb = ws + 1048576 + 262144;           // 1048576 f
  float* attn = fusedb + 1048576;                  // 524288 f

  proj_kernel<<<dim3(24, 16), 256, 0, stream>>>(query, key, value, W, pb, qh,
                                                kh, vh);
  score_kernel<<<1024, 256, 0, stream>>>(qh, kh, vh, cbias, fusedb);
  softmax_attn_kernel<<<8192, 64, 0, stream>>>(fusedb, qh, attn);
  outproj_kernel<<<dim3(8, 16), 256, 0, stream>>>(attn, out_w, out_b, out);
}